// Round 7
// baseline (1330.450 us; speedup 1.0000x reference)
//
#include <hip/hip_runtime.h>
#include <math.h>

#define NPTS 65536
#define DIMD 256
#define KCB  4096
#define MARGIN 2.0f

// d_out float32 offsets (reference tuple order, flattened)
#define O_ZQ   0
#define O_IDX  16777216
#define O_LOSS 16842752
#define O_PERP 16842753
#define O_CS   16842754
#define O_EMAW 16846850
#define O_W    17895426

// scratch inside d_out O_ZQ region (16,777,216 floats; dead until k_zq):
#define OFF_WSW   8388608      // swizzled w bf16: 256 grp x 8 chunk x 1024 B
#define OFF_CCNT  8912896      // 65536 ints
#define OFF_CIDS  8978432      // 65536 x 16 ints
#define OFF_OFFS  10027008     // 4097 ints
#define OFF_CUR   10031232     // 4096 ints
#define OFF_ROWS  10035328     // 65536 ints
#define OFF_GMIN  10100864     // 65536 uints
#define OFF_CHOF  10166400     // 4097 ints (chunk prefix)
#define OFF_BMIN  10240000     // 65536 x 16 floats (per-row per-256-code-block min)
#define OFF_RL    11288576     // 16 x PADL ints (per-block row lists)
// zz -> EMAW region [0,65536); wwg -> EMAW [65536,69632)  (dead before k_fill zeroes dw)

#define CHK 64                 // rows per dw chunk
#define MAXCHUNKS 5120         // 4096 + 65536/64 upper bound
#define PADL 65600             // row-list stride

// pass0 ring: 4 LDS slots x 2 groups (16 KB each), prefetch depth 2.
#define RING0 4
#define NSLOT 64

typedef __attribute__((ext_vector_type(8))) short short8;   // 8 bf16
typedef __attribute__((ext_vector_type(4))) float f32x4;

__device__ __forceinline__ unsigned short f2bf(float f) {   // RNE
    unsigned u = __float_as_uint(f);
    return (unsigned short)((u + 0x7FFF + ((u >> 16) & 1)) >> 16);
}
__device__ __forceinline__ unsigned encf(float f) {         // order-preserving
    unsigned u = __float_as_uint(f);
    return (u >> 31) ? ~u : (u | 0x80000000u);
}
__device__ __forceinline__ float decf(unsigned e) {
    unsigned u = (e & 0x80000000u) ? (e & 0x7fffffffu) : ~e;
    return __uint_as_float(u);
}

// ------- merged prep: z->bf16 rows + zz, w->bf16 swizzle + wwg, + zero-init
__global__ void k_prep(const float* __restrict__ zsrc, const float* __restrict__ wsrc,
                       unsigned* __restrict__ zdst, unsigned* __restrict__ wdst,
                       float* __restrict__ zz, float* __restrict__ wwg,
                       unsigned* __restrict__ gmin, int* __restrict__ ccnt,
                       float* __restrict__ cs, float* __restrict__ scal,
                       int* __restrict__ bcnt, unsigned* __restrict__ ticks) {
    int b = blockIdx.x, t = threadIdx.x;
    int l = t & 63;
    if (b < NPTS / 4) {
        int row = b * 4 + (t >> 6);
        float4 v = ((const float4*)(zsrc + (size_t)row * DIMD))[l];
        uint2 pk = make_uint2(f2bf(v.x) | (f2bf(v.y) << 16),
                              f2bf(v.z) | (f2bf(v.w) << 16));
        ((uint2*)zdst)[(size_t)row * 64 + l] = pk;
        float s = v.x*v.x + v.y*v.y + v.z*v.z + v.w*v.w;
        #pragma unroll
        for (int off = 32; off; off >>= 1) s += __shfl_down(s, off);
        if (l == 0) zz[row] = s;
        if (t < 4) gmin[b * 4 + t] = 0xFFFFFFFFu;
        else if (t < 8) ccnt[b * 4 + (t - 4)] = 0;
    } else {
        int b2 = b - NPTS / 4;
        int row = b2 * 4 + (t >> 6);
        float4 v = ((const float4*)(wsrc + (size_t)row * DIMD))[l];
        uint2 pk = make_uint2(f2bf(v.x) | (f2bf(v.y) << 16),
                              f2bf(v.z) | (f2bf(v.w) << 16));
        int g = row >> 4, n16 = row & 15;
        int c = l >> 3, q = (l >> 1) & 3, half = l & 1;
        ((uint2*)wdst)[g * 1024 + c * 128 + (q * 16 + n16) * 2 + half] = pk;
        float s = v.x*v.x + v.y*v.y + v.z*v.z + v.w*v.w;
        #pragma unroll
        for (int off = 32; off; off >>= 1) s += __shfl_down(s, off);
        if (l == 0) wwg[row] = s;
        if (t < 4) cs[b2 * 4 + t] = 0.f;
        if (b2 == 0) {
            scal[t] = 0.f;
            if (t < 16) bcnt[t] = 0;
            if (t < 2)  ticks[t] = 0u;
        }
    }
}

// ---------------- pass 0: per-row bf16-core min + per-block min ------------
// Ring pipeline, 2 groups per slot, 64 slots. Accumulators are BIAS-INITed
// to -0.5*||w||^2 so core = -2*acc; the per-group epilogue is 16 v_max only
// (min-core = -2*max-acc, -2x applied at block boundaries / final).
__launch_bounds__(256, 2)
__global__ void k_pass0(const unsigned* __restrict__ zbf,
                        const uint4* __restrict__ wsw4,
                        const float* __restrict__ wwg,
                        unsigned* __restrict__ gmin,
                        float* __restrict__ bmin) {
    __shared__ __align__(16) char smem[RING0 * 16384];
    __shared__ float lds_ww[2048];
    const int t = threadIdx.x, wv = t >> 6, l = t & 63;
    const int q = l >> 4, n16 = l & 15;
    const int rb    = blockIdx.x >> 1;
    const int half  = blockIdx.x & 1;
    const int row0  = rb * 256 + wv * 64;
    const int g0    = half * 128;
    const int ph0s  = ((blockIdx.x * 3) & 7) * 8;   // slot stagger, 8-aligned

    union U { uint4 u; short8 s; } afr[4][8];
    #pragma unroll
    for (int s = 0; s < 4; ++s) {
        const char* zb = (const char*)zbf + ((size_t)(row0 + s * 16 + n16) << 9) + q * 16;
        #pragma unroll
        for (int c = 0; c < 8; ++c) afr[s][c].u = *(const uint4*)(zb + c * 64);
    }

    auto stage = [&](int buf, int s) {
        const int sa = (ph0s + s) & 63;
        const uint4* srcb = wsw4 + (size_t)(g0 + sa * 2) * 512;
        #pragma unroll
        for (int j = 0; j < 4; ++j) {
            int rrow = j * 4 + wv;
            __builtin_amdgcn_global_load_lds(
                (const __attribute__((address_space(1))) unsigned*)(srcb + rrow * 64 + l),
                (__attribute__((address_space(3))) unsigned*)(&smem[buf * 16384 + rrow * 1024]),
                16, 0, 0);
        }
    };

    for (int i = t; i < 2048; i += 256) lds_ww[i] = wwg[g0 * 16 + i];
    stage(0, 0);
    stage(1, 1);
    __syncthreads();                                // full drain once (prologue)

    float minv[16], bm[16];                         // maxima of acc now
    #pragma unroll
    for (int i = 0; i < 16; ++i) { minv[i] = -3.0e38f; bm[i] = -3.0e38f; }

    int buf = 0, sbuf = 2;
    #pragma unroll 1
    for (int s = 0; s < NSLOT; ++s) {
        if (s < NSLOT - 2) {
            stage(sbuf, s + 2);
            sbuf = (sbuf + 1) & 3;
            asm volatile("s_waitcnt vmcnt(8)" ::: "memory");
        } else {
            asm volatile("s_waitcnt vmcnt(0)" ::: "memory");
        }
        __builtin_amdgcn_s_barrier();
        const char* sbase = smem + buf * 16384;
        buf = (buf + 1) & 3;
        const int sa = (ph0s + s) & 63;
        #pragma unroll
        for (int g2 = 0; g2 < 2; ++g2) {
            float bias = -0.5f * lds_ww[(sa * 2 + g2) * 16 + n16];
            f32x4 acc[4];
            #pragma unroll
            for (int s4 = 0; s4 < 4; ++s4) acc[s4] = (f32x4){bias, bias, bias, bias};
            __builtin_amdgcn_s_setprio(1);
            #pragma unroll
            for (int c = 0; c < 8; ++c) {
                U bf; bf.u = *(const uint4*)(sbase + g2 * 8192 + c * 1024 + (l << 4));
                #pragma unroll
                for (int s4 = 0; s4 < 4; ++s4)
                    acc[s4] = __builtin_amdgcn_mfma_f32_16x16x32_bf16(afr[s4][c].s, bf.s, acc[s4], 0, 0, 0);
            }
            __builtin_amdgcn_s_setprio(0);
            #pragma unroll
            for (int s4 = 0; s4 < 4; ++s4)
                #pragma unroll
                for (int r = 0; r < 4; ++r)
                    bm[s4*4+r] = fmaxf(bm[s4*4+r], acc[s4][r]);
        }
        if ((s & 7) == 7) {                         // end of a 256-code block
            const int blk = (g0 >> 4) + (((ph0s + (s & ~7)) & 63) >> 3);
            #pragma unroll
            for (int i = 0; i < 16; ++i) {
                float m = bm[i];
                minv[i] = fmaxf(minv[i], m);
                #pragma unroll
                for (int msk = 1; msk < 16; msk <<= 1) m = fmaxf(m, __shfl_xor(m, msk));
                if (n16 == 0)
                    bmin[(size_t)(row0 + (i >> 2) * 16 + q * 4 + (i & 3)) * 16 + blk] = -2.0f * m;
                bm[i] = -3.0e38f;
            }
        }
    }

    #pragma unroll
    for (int i = 0; i < 16; ++i) {
        float m = minv[i];
        #pragma unroll
        for (int msk = 1; msk < 16; msk <<= 1) m = fmaxf(m, __shfl_xor(m, msk));
        if (n16 == 0)
            atomicMin(&gmin[row0 + (i >> 2) * 16 + q * 4 + (i & 3)], encf(-2.0f * m));
    }
}

// -------- block-select: per row, append to qualifying blocks' row lists ----
__global__ void k_bsel(const unsigned* __restrict__ gmin,
                       const float* __restrict__ bmin,
                       int* __restrict__ bcnt, int* __restrict__ rlist) {
    __shared__ int lcnt[16], lbase[16], lcur[16];
    int t = threadIdx.x;
    if (t < 16) { lcnt[t] = 0; lcur[t] = 0; }
    __syncthreads();
    int row = blockIdx.x * 256 + t;
    float thr = decf(gmin[row]) + MARGIN;
    const float* bm = bmin + (size_t)row * 16;
    unsigned qual = 0;
    #pragma unroll
    for (int b = 0; b < 16; ++b)
        if (bm[b] <= thr) { qual |= (1u << b); atomicAdd(&lcnt[b], 1); }
    __syncthreads();
    if (t < 16) lbase[t] = atomicAdd(&bcnt[t], lcnt[t]);
    __syncthreads();
    #pragma unroll
    for (int b = 0; b < 16; ++b)
        if (qual & (1u << b)) {
            int p = atomicAdd(&lcur[b], 1);
            rlist[b * PADL + lbase[b] + p] = row;
        }
}

// ---------------- pass 1: emit candidates over pruned ragged tiles --------
__launch_bounds__(256, 2)
__global__ void k_pass1(const unsigned* __restrict__ zbf,
                        const uint4* __restrict__ wsw4,
                        const float* __restrict__ wwg,
                        const unsigned* __restrict__ gmin,
                        const int* __restrict__ bcnt,
                        const int* __restrict__ rlist,
                        int* __restrict__ ccnt,
                        int* __restrict__ cids) {
    const int t = threadIdx.x, wv = t >> 6, l = t & 63;
    const int q = l >> 4, n16 = l & 15;
    int bc[16];
    #pragma unroll
    for (int i = 0; i < 16; ++i) bc[i] = bcnt[i];
    int tp[17]; tp[0] = 0;
    #pragma unroll
    for (int i = 0; i < 16; ++i) tp[i + 1] = tp[i] + ((bc[i] + 63) >> 6);
    const int ntiles = tp[16];

    for (int tile = blockIdx.x * 4 + wv; tile < ntiles; tile += 2048) {
        int b = 0, tpb = 0, nb = bc[0];
        #pragma unroll
        for (int i = 1; i < 16; ++i)
            if (tp[i] <= tile) { b = i; tpb = tp[i]; nb = bc[i]; }
        const int lim = nb - (tile - tpb) * 64;
        const int* rl = rlist + b * PADL + (tile - tpb) * 64;

        union U { uint4 u; short8 s; } afr[4][8];
        #pragma unroll
        for (int s = 0; s < 4; ++s) {
            int idx = s * 16 + n16;
            int r = (idx < lim) ? rl[idx] : -1;
            int rr = r < 0 ? 0 : r;
            const char* zb = (const char*)zbf + ((size_t)rr << 9) + q * 16;
            #pragma unroll
            for (int c = 0; c < 8; ++c) afr[s][c].u = *(const uint4*)(zb + c * 64);
        }
        int rowid[16];
        float thr[16];
        #pragma unroll
        for (int i = 0; i < 16; ++i) {
            int idx = (i >> 2) * 16 + q * 4 + (i & 3);
            int r = (idx < lim) ? rl[idx] : -1;
            rowid[i] = r;
            thr[i] = -3.0e38f;
            if (r >= 0) thr[i] = decf(gmin[r]) + MARGIN;
        }

        #pragma unroll 2
        for (int g = 0; g < 16; ++g) {
            const int gg = b * 16 + g;
            const uint4* wp = wsw4 + (size_t)gg * 512 + l;
            f32x4 acc[4];
            #pragma unroll
            for (int s = 0; s < 4; ++s) acc[s] = (f32x4){0.f, 0.f, 0.f, 0.f};
            #pragma unroll
            for (int c = 0; c < 8; ++c) {
                U bf; bf.u = wp[c * 64];
                #pragma unroll
                for (int s = 0; s < 4; ++s)
                    acc[s] = __builtin_amdgcn_mfma_f32_16x16x32_bf16(afr[s][c].s, bf.s, acc[s], 0, 0, 0);
            }
            float wwv = wwg[gg * 16 + n16];
            #pragma unroll
            for (int s = 0; s < 4; ++s)
                #pragma unroll
                for (int r = 0; r < 4; ++r) {
                    float core = fmaf(-2.f, acc[s][r], wwv);
                    if (core <= thr[s*4+r]) {
                        int row = rowid[s * 4 + r];
                        int pos = atomicAdd(&ccnt[row], 1);
                        if (pos < 16) cids[row * 16 + pos] = gg * 16 + n16;
                    }
                }
        }
    }
}

// ------- fp32 rescore of candidates; LAST BLOCK runs the mid-stage --------
// (prefix sums offs/cursor/choffs + cs EMA + perplexity)
__global__ void k_refine(const float* __restrict__ z,
                         const float* __restrict__ w,
                         const float* __restrict__ zz,
                         const float* __restrict__ wwg,
                         const int* __restrict__ ccnt,
                         const int* __restrict__ cids,
                         const float* __restrict__ ema_cs,
                         float* __restrict__ counts,   // == cs_io (out+O_CS)
                         int*   __restrict__ idxi,
                         float* __restrict__ idxf,
                         int* __restrict__ offs, int* __restrict__ cursor,
                         int* __restrict__ choffs,
                         float* __restrict__ perp,
                         unsigned* __restrict__ tick) {
    __shared__ int lastb;
    __shared__ int sc[256];
    __shared__ float2 redf[4];
    __shared__ float sn;
    int l   = threadIdx.x & 63;
    int row = blockIdx.x * 4 + (threadIdx.x >> 6);
    int n = ccnt[row]; if (n > 16) n = 16;
    float4 zv = ((const float4*)(z + (size_t)row * DIMD))[l];
    float zzv = zz[row];
    float bd = 3.0e38f; int bi = 0x7fffffff;
    for (int j = 0; j < n; ++j) {
        int k = cids[row * 16 + j];
        float4 wv = ((const float4*)(w + (size_t)k * DIMD))[l];
        float s = zv.x*wv.x + zv.y*wv.y + zv.z*wv.z + zv.w*wv.w;
        #pragma unroll
        for (int off = 32; off; off >>= 1) s += __shfl_xor(s, off);
        float d = (zzv + wwg[k]) - 2.0f * s;
        if (d < bd || (d == bd && k < bi)) { bd = d; bi = k; }
    }
    if (l == 0) {
        idxi[row] = bi;
        idxf[row] = (float)bi;
        atomicAdd(&counts[bi], 1.0f);
    }

    // ---- last-block ticket: all waves' counts atomics drained by barrier ----
    __syncthreads();
    if (threadIdx.x == 0) {
        __threadfence();
        lastb = (atomicAdd(tick, 1u) == (unsigned)(gridDim.x - 1)) ? 1 : 0;
    }
    __syncthreads();
    if (!lastb) return;
    __threadfence();

    int t = threadIdx.x;                 // 256 threads, 16 entries each
    int c[16]; int s = 0;
    #pragma unroll
    for (int i = 0; i < 16; ++i) {
        c[i] = (int)__hip_atomic_load(&counts[t * 16 + i], __ATOMIC_RELAXED,
                                      __HIP_MEMORY_SCOPE_AGENT);
        s += c[i];
    }
    sc[t] = s;
    __syncthreads();
    for (int d = 1; d < 256; d <<= 1) {
        int v = (t >= d) ? sc[t - d] : 0;
        __syncthreads();
        sc[t] += v;
        __syncthreads();
    }
    int o = sc[t] - s;
    #pragma unroll
    for (int i = 0; i < 16; ++i) { offs[t*16+i] = o; cursor[t*16+i] = o; o += c[i]; }
    if (t == 255) offs[4096] = sc[255];
    __syncthreads();

    int ch[16]; int s2 = 0;
    #pragma unroll
    for (int i = 0; i < 16; ++i) { ch[i] = (c[i] + CHK - 1) / CHK; s2 += ch[i]; }
    sc[t] = s2;
    __syncthreads();
    for (int d = 1; d < 256; d <<= 1) {
        int v = (t >= d) ? sc[t - d] : 0;
        __syncthreads();
        sc[t] += v;
        __syncthreads();
    }
    int o2 = sc[t] - s2;
    #pragma unroll
    for (int i = 0; i < 16; ++i) { choffs[t*16+i] = o2; o2 += ch[i]; }
    if (t == 255) choffs[4096] = sc[255];

    // cluster-size EMA + perplexity
    float csd[16]; float nl = 0.f, el = 0.f;
    #pragma unroll
    for (int i = 0; i < 16; ++i) {
        float cf = (float)c[i];
        float cd = ema_cs[t * 16 + i] * 0.99f + 0.01f * cf;
        csd[i] = cd;
        nl += cd;
        float p = cf * (1.0f / 65536.0f);
        el += p * logf(p + 1e-10f);
    }
    #pragma unroll
    for (int off = 32; off; off >>= 1) { nl += __shfl_down(nl, off); el += __shfl_down(el, off); }
    if ((t & 63) == 0) redf[t >> 6] = make_float2(nl, el);
    __syncthreads();
    if (t == 0) {
        float nn = 0.f, e = 0.f;
        for (int i = 0; i < 4; ++i) { nn += redf[i].x; e += redf[i].y; }
        sn = nn;
        perp[0] = expf(-e);
    }
    __syncthreads();
    float nn = sn;
    float scale = nn / (nn + 4096.0f * 1e-5f);
    #pragma unroll
    for (int i = 0; i < 16; ++i)
        counts[t * 16 + i] = (csd[i] + 1e-5f) * scale;
}

// ---------------- fill inverted row lists + zero dw region ----------------
__global__ void k_fill(const int* __restrict__ idxi, int* __restrict__ cursor,
                       int* __restrict__ rows, float* __restrict__ dw) {
    int r = blockIdx.x * 256 + threadIdx.x;
    float4* p = (float4*)(dw + (size_t)r * 16);
    float4 zf = make_float4(0.f, 0.f, 0.f, 0.f);
    p[0] = zf; p[1] = zf; p[2] = zf; p[3] = zf;
    int k = idxi[r];
    int pos = atomicAdd(&cursor[k], 1);
    rows[pos] = r;
}

// ---------------- dw[k,:] += sum of z rows in chunk (chunk-parallel) ------
__global__ void k_dw(const float* __restrict__ z, const int* __restrict__ offs,
                     const int* __restrict__ choffs, const int* __restrict__ rows,
                     float* __restrict__ dw) {
    __shared__ float4 part[4][64];
    int b = blockIdx.x;
    if (b >= choffs[KCB]) return;
    int lo = 0, hi = KCB;
    while (hi - lo > 1) { int mid = (lo + hi) >> 1; if (choffs[mid] <= b) lo = mid; else hi = mid; }
    int k  = lo;
    int ci = b - choffs[k];
    int o0 = offs[k] + ci * CHK;
    int o1 = offs[k + 1]; if (o1 > o0 + CHK) o1 = o0 + CHK;
    int l = threadIdx.x & 63, j = threadIdx.x >> 6;
    float4 a = make_float4(0.f, 0.f, 0.f, 0.f);
    for (int i = o0 + j; i < o1; i += 4) {
        int r = rows[i];
        float4 v = ((const float4*)(z + (size_t)r * DIMD))[l];
        a.x += v.x; a.y += v.y; a.z += v.z; a.w += v.w;
    }
    part[j][l] = a;
    __syncthreads();
    if (j == 0) {
        float4 bb = part[0][l], c = part[1][l], d = part[2][l], e = part[3][l];
        a = make_float4(bb.x+c.x+d.x+e.x, bb.y+c.y+d.y+e.y,
                        bb.z+c.z+d.z+e.z, bb.w+c.w+d.w+e.w);
        float* p = dw + (size_t)k * DIMD + l * 4;
        if (choffs[k + 1] - choffs[k] == 1) {
            *(float4*)p = a;
        } else {
            atomicAdd(p + 0, a.x); atomicAdd(p + 1, a.y);
            atomicAdd(p + 2, a.z); atomicAdd(p + 3, a.w);
        }
    }
}

// ---------------- new_ema_w (in-place over dw) + new_weight ----------------
__global__ void k_emaw(const float* __restrict__ ema_w,
                       const float* __restrict__ cs,
                       float* __restrict__ emaw_io,
                       float* __restrict__ wout) {
    int i = (blockIdx.x * 256 + threadIdx.x) * 4;
    int k = i >> 8;
    float4 dv = *(const float4*)(emaw_io + i);
    float4 ev = *(const float4*)(ema_w + i);
    float c = cs[k];
    float4 ne;
    ne.x = ev.x * 0.99f + 0.01f * dv.x;
    ne.y = ev.y * 0.99f + 0.01f * dv.y;
    ne.z = ev.z * 0.99f + 0.01f * dv.z;
    ne.w = ev.w * 0.99f + 0.01f * dv.w;
    *(float4*)(emaw_io + i) = ne;
    float4 nw = make_float4(ne.x / c, ne.y / c, ne.z / c, ne.w / c);
    *(float4*)(wout + i) = nw;
}

// ------- z_q gather + straight-through + loss; LAST BLOCK finalizes loss --
__global__ void k_zq(const float* __restrict__ z,
                     const float* __restrict__ wnew,
                     const int* __restrict__ idxi,
                     float* __restrict__ zq,
                     float* __restrict__ sqacc,     // 256 accumulators
                     unsigned* __restrict__ tick,
                     float* __restrict__ loss) {
    __shared__ float red[4];
    __shared__ int lastb;
    int i = (blockIdx.x * 256 + threadIdx.x) * 4;
    int n = i >> 8;
    int d = i & 255;
    int k = idxi[n];
    float4 wv = *(const float4*)(wnew + (k << 8) + d);
    float4 zv = *(const float4*)(z + i);
    float4 o;
    o.x = zv.x + (wv.x - zv.x);
    o.y = zv.y + (wv.y - zv.y);
    o.z = zv.z + (wv.z - zv.z);
    o.w = zv.w + (wv.w - zv.w);
    *(float4*)(zq + i) = o;
    float dx = wv.x - zv.x, dy = wv.y - zv.y, dz = wv.z - zv.z, dw_ = wv.w - zv.w;
    float s = dx*dx + dy*dy + dz*dz + dw_*dw_;
    #pragma unroll
    for (int off = 32; off; off >>= 1) s += __shfl_down(s, off);
    int lane = threadIdx.x & 63;
    if (lane == 0) red[threadIdx.x >> 6] = s;
    __syncthreads();
    if (threadIdx.x == 0) {
        atomicAdd(&sqacc[blockIdx.x & 255], red[0] + red[1] + red[2] + red[3]);
        __threadfence();
        lastb = (atomicAdd(tick, 1u) == (unsigned)(gridDim.x - 1)) ? 1 : 0;
    }
    __syncthreads();
    if (!lastb) return;
    __threadfence();
    int t = threadIdx.x;
    float s2 = __hip_atomic_load(&sqacc[t], __ATOMIC_RELAXED, __HIP_MEMORY_SCOPE_AGENT);
    #pragma unroll
    for (int off = 32; off; off >>= 1) s2 += __shfl_down(s2, off);
    if ((t & 63) == 0) red[t >> 6] = s2;
    __syncthreads();
    if (t == 0)
        loss[0] = 1.25f * (red[0] + red[1] + red[2] + red[3]) * (1.0f / 16777216.0f);
}

extern "C" void kernel_launch(void* const* d_in, const int* in_sizes, int n_in,
                              void* d_out, int out_size, void* d_ws, size_t ws_size,
                              hipStream_t stream) {
    const float* z      = (const float*)d_in[0];
    const float* weight = (const float*)d_in[1];
    const float* ema_w  = (const float*)d_in[2];
    const float* ema_cs = (const float*)d_in[3];
    float* out = (float*)d_out;
    float* ws  = (float*)d_ws;

    int*      bcnt  = (int*)ws;               // 16 ints
    float*    scal  = ws + 4096;              // 256 floats
    unsigned* ticks = (unsigned*)(ws + 4608); // 2 uints
    int*      idxi  = (int*)(ws + 8192);      // 65536 ints

    unsigned* zbf    = (unsigned*)(out + O_ZQ);
    uint4*    wsw4   = (uint4*)(out + O_ZQ + OFF_WSW);
    int*      ccnt   = (int*)(out + O_ZQ + OFF_CCNT);
    int*      cids   = (int*)(out + O_ZQ + OFF_CIDS);
    int*      offs   = (int*)(out + O_ZQ + OFF_OFFS);
    int*      cursor = (int*)(out + O_ZQ + OFF_CUR);
    int*      rows   = (int*)(out + O_ZQ + OFF_ROWS);
    unsigned* gmin   = (unsigned*)(out + O_ZQ + OFF_GMIN);
    int*      choffs = (int*)(out + O_ZQ + OFF_CHOF);
    float*    bmin   = out + O_ZQ + OFF_BMIN;
    int*      rlist  = (int*)(out + O_ZQ + OFF_RL);
    float*    zz     = out + O_EMAW;           // dead before k_fill zeroes dw
    float*    wwg    = out + O_EMAW + 65536;

    k_prep   <<<NPTS / 4 + KCB / 4, 256, 0, stream>>>(z, weight, zbf,
                                                      (unsigned*)wsw4, zz, wwg,
                                                      gmin, ccnt, out + O_CS,
                                                      scal, bcnt, ticks);
    k_pass0  <<<512, 256, 0, stream>>>(zbf, wsw4, wwg, gmin, bmin);
    k_bsel   <<<NPTS / 256, 256, 0, stream>>>(gmin, bmin, bcnt, rlist);
    k_pass1  <<<512, 256, 0, stream>>>(zbf, wsw4, wwg, gmin, bcnt, rlist,
                                       ccnt, cids);
    k_refine <<<NPTS / 4, 256, 0, stream>>>(z, weight, zz, wwg, ccnt, cids,
                                            ema_cs, out + O_CS, idxi,
                                            out + O_IDX, offs, cursor, choffs,
                                            out + O_PERP, ticks + 0);
    k_fill   <<<NPTS / 256, 256, 0, stream>>>(idxi, cursor, rows, out + O_EMAW);
    k_dw     <<<MAXCHUNKS, 256, 0, stream>>>(z, offs, choffs, rows, out + O_EMAW);
    k_emaw   <<<(KCB * DIMD) / 1024, 256, 0, stream>>>(ema_w, out + O_CS,
                                                       out + O_EMAW, out + O_W);
    k_zq     <<<(NPTS * DIMD) / 1024, 256, 0, stream>>>(z, out + O_W, idxi,
                                                        out + O_ZQ, scal,
                                                        ticks + 1, out + O_LOSS);
}

// Round 9
// 437.753 us; speedup vs baseline: 3.0393x; 3.0393x over previous
//
#include <hip/hip_runtime.h>
#include <math.h>

#define NPTS 65536
#define DIMD 256
#define KCB  4096
#define MARGIN 2.0f

// d_out float32 offsets (reference tuple order, flattened)
#define O_ZQ   0
#define O_IDX  16777216
#define O_LOSS 16842752
#define O_PERP 16842753
#define O_CS   16842754
#define O_EMAW 16846850
#define O_W    17895426

// scratch inside d_out O_ZQ region (16,777,216 floats; dead until k_zq):
#define OFF_WSW   8388608      // swizzled w bf16: 256 grp x 8 chunk x 1024 B
#define OFF_CCNT  8912896      // 65536 ints
#define OFF_CIDS  8978432      // 65536 x 16 ints
#define OFF_OFFS  10027008     // 4097 ints
#define OFF_CUR   10031232     // 4096 ints
#define OFF_ROWS  10035328     // 65536 ints
#define OFF_GMIN  10100864     // 65536 uints
#define OFF_CHOF  10166400     // 4097 ints (chunk prefix)
#define OFF_BMIN  10240000     // 65536 x 16 floats (per-row per-256-code-block min)
#define OFF_RL    11288576     // 16 x PADL ints (per-block row lists)
// zz -> EMAW region [0,65536); wwg -> EMAW [65536,69632)  (dead before k_fill zeroes dw)

#define CHK 64                 // rows per dw chunk
#define MAXCHUNKS 5120         // 4096 + 65536/64 upper bound
#define PADL 65600             // row-list stride

// pass0 ring: 4 LDS slots x 2 groups (16 KB each), prefetch depth 2.
#define RING0 4
#define NSLOT 64

typedef __attribute__((ext_vector_type(8))) short short8;   // 8 bf16
typedef __attribute__((ext_vector_type(4))) float f32x4;

__device__ __forceinline__ unsigned short f2bf(float f) {   // RNE
    unsigned u = __float_as_uint(f);
    return (unsigned short)((u + 0x7FFF + ((u >> 16) & 1)) >> 16);
}
__device__ __forceinline__ unsigned encf(float f) {         // order-preserving
    unsigned u = __float_as_uint(f);
    return (u >> 31) ? ~u : (u | 0x80000000u);
}
__device__ __forceinline__ float decf(unsigned e) {
    unsigned u = (e & 0x80000000u) ? (e & 0x7fffffffu) : ~e;
    return __uint_as_float(u);
}

// ------- merged prep: z->bf16 rows + zz, w->bf16 swizzle + wwg, + zero-init
__global__ void k_prep(const float* __restrict__ zsrc, const float* __restrict__ wsrc,
                       unsigned* __restrict__ zdst, unsigned* __restrict__ wdst,
                       float* __restrict__ zz, float* __restrict__ wwg,
                       unsigned* __restrict__ gmin, int* __restrict__ ccnt,
                       float* __restrict__ cs, float* __restrict__ scal,
                       int* __restrict__ bcnt) {
    int b = blockIdx.x, t = threadIdx.x;
    int l = t & 63;
    if (b < NPTS / 4) {
        int row = b * 4 + (t >> 6);
        float4 v = ((const float4*)(zsrc + (size_t)row * DIMD))[l];
        uint2 pk = make_uint2(f2bf(v.x) | (f2bf(v.y) << 16),
                              f2bf(v.z) | (f2bf(v.w) << 16));
        ((uint2*)zdst)[(size_t)row * 64 + l] = pk;
        float s = v.x*v.x + v.y*v.y + v.z*v.z + v.w*v.w;
        #pragma unroll
        for (int off = 32; off; off >>= 1) s += __shfl_down(s, off);
        if (l == 0) zz[row] = s;
        if (t < 4) gmin[b * 4 + t] = 0xFFFFFFFFu;
        else if (t < 8) ccnt[b * 4 + (t - 4)] = 0;
    } else {
        int b2 = b - NPTS / 4;
        int row = b2 * 4 + (t >> 6);
        float4 v = ((const float4*)(wsrc + (size_t)row * DIMD))[l];
        uint2 pk = make_uint2(f2bf(v.x) | (f2bf(v.y) << 16),
                              f2bf(v.z) | (f2bf(v.w) << 16));
        int g = row >> 4, n16 = row & 15;
        int c = l >> 3, q = (l >> 1) & 3, half = l & 1;
        ((uint2*)wdst)[g * 1024 + c * 128 + (q * 16 + n16) * 2 + half] = pk;
        float s = v.x*v.x + v.y*v.y + v.z*v.z + v.w*v.w;
        #pragma unroll
        for (int off = 32; off; off >>= 1) s += __shfl_down(s, off);
        if (l == 0) wwg[row] = s;
        if (t < 4) cs[b2 * 4 + t] = 0.f;
        if (b2 == 0) { scal[t] = 0.f; if (t < 16) bcnt[t] = 0; }
    }
}

// ---------------- pass 0: per-row bf16-core min + per-block min ------------
// Ring pipeline, 2 groups per slot, 64 slots. Accumulators are BIAS-INITed
// to -0.5*||w||^2 so core = -2*acc; the per-group epilogue is 16 v_max only
// (min-core = -2*max-acc, -2x applied at block boundaries / final).
// [bias-init correctness validated in round 7: absmax unchanged]
__launch_bounds__(256, 2)
__global__ void k_pass0(const unsigned* __restrict__ zbf,
                        const uint4* __restrict__ wsw4,
                        const float* __restrict__ wwg,
                        unsigned* __restrict__ gmin,
                        float* __restrict__ bmin) {
    __shared__ __align__(16) char smem[RING0 * 16384];
    __shared__ float lds_ww[2048];
    const int t = threadIdx.x, wv = t >> 6, l = t & 63;
    const int q = l >> 4, n16 = l & 15;
    const int rb    = blockIdx.x >> 1;
    const int half  = blockIdx.x & 1;
    const int row0  = rb * 256 + wv * 64;
    const int g0    = half * 128;
    const int ph0s  = ((blockIdx.x * 3) & 7) * 8;   // slot stagger, 8-aligned

    union U { uint4 u; short8 s; } afr[4][8];
    #pragma unroll
    for (int s = 0; s < 4; ++s) {
        const char* zb = (const char*)zbf + ((size_t)(row0 + s * 16 + n16) << 9) + q * 16;
        #pragma unroll
        for (int c = 0; c < 8; ++c) afr[s][c].u = *(const uint4*)(zb + c * 64);
    }

    auto stage = [&](int buf, int s) {
        const int sa = (ph0s + s) & 63;
        const uint4* srcb = wsw4 + (size_t)(g0 + sa * 2) * 512;
        #pragma unroll
        for (int j = 0; j < 4; ++j) {
            int rrow = j * 4 + wv;
            __builtin_amdgcn_global_load_lds(
                (const __attribute__((address_space(1))) unsigned*)(srcb + rrow * 64 + l),
                (__attribute__((address_space(3))) unsigned*)(&smem[buf * 16384 + rrow * 1024]),
                16, 0, 0);
        }
    };

    for (int i = t; i < 2048; i += 256) lds_ww[i] = wwg[g0 * 16 + i];
    stage(0, 0);
    stage(1, 1);
    __syncthreads();                                // full drain once (prologue)

    float minv[16], bm[16];                         // maxima of acc
    #pragma unroll
    for (int i = 0; i < 16; ++i) { minv[i] = -3.0e38f; bm[i] = -3.0e38f; }

    int buf = 0, sbuf = 2;
    #pragma unroll 1
    for (int s = 0; s < NSLOT; ++s) {
        if (s < NSLOT - 2) {
            stage(sbuf, s + 2);
            sbuf = (sbuf + 1) & 3;
            asm volatile("s_waitcnt vmcnt(8)" ::: "memory");
        } else {
            asm volatile("s_waitcnt vmcnt(0)" ::: "memory");
        }
        __builtin_amdgcn_s_barrier();
        const char* sbase = smem + buf * 16384;
        buf = (buf + 1) & 3;
        const int sa = (ph0s + s) & 63;
        #pragma unroll
        for (int g2 = 0; g2 < 2; ++g2) {
            float bias = -0.5f * lds_ww[(sa * 2 + g2) * 16 + n16];
            f32x4 acc[4];
            #pragma unroll
            for (int s4 = 0; s4 < 4; ++s4) acc[s4] = (f32x4){bias, bias, bias, bias};
            __builtin_amdgcn_s_setprio(1);
            #pragma unroll
            for (int c = 0; c < 8; ++c) {
                U bf; bf.u = *(const uint4*)(sbase + g2 * 8192 + c * 1024 + (l << 4));
                #pragma unroll
                for (int s4 = 0; s4 < 4; ++s4)
                    acc[s4] = __builtin_amdgcn_mfma_f32_16x16x32_bf16(afr[s4][c].s, bf.s, acc[s4], 0, 0, 0);
            }
            __builtin_amdgcn_s_setprio(0);
            #pragma unroll
            for (int s4 = 0; s4 < 4; ++s4)
                #pragma unroll
                for (int r = 0; r < 4; ++r)
                    bm[s4*4+r] = fmaxf(bm[s4*4+r], acc[s4][r]);
        }
        if ((s & 7) == 7) {                         // end of a 256-code block
            const int blk = (g0 >> 4) + (((ph0s + (s & ~7)) & 63) >> 3);
            #pragma unroll
            for (int i = 0; i < 16; ++i) {
                float m = bm[i];
                minv[i] = fmaxf(minv[i], m);
                #pragma unroll
                for (int msk = 1; msk < 16; msk <<= 1) m = fmaxf(m, __shfl_xor(m, msk));
                if (n16 == 0)
                    bmin[(size_t)(row0 + (i >> 2) * 16 + q * 4 + (i & 3)) * 16 + blk] = -2.0f * m;
                bm[i] = -3.0e38f;
            }
        }
    }

    #pragma unroll
    for (int i = 0; i < 16; ++i) {
        float m = minv[i];
        #pragma unroll
        for (int msk = 1; msk < 16; msk <<= 1) m = fmaxf(m, __shfl_xor(m, msk));
        if (n16 == 0)
            atomicMin(&gmin[row0 + (i >> 2) * 16 + q * 4 + (i & 3)], encf(-2.0f * m));
    }
}

// -------- block-select: per row, append to qualifying blocks' row lists ----
__global__ void k_bsel(const unsigned* __restrict__ gmin,
                       const float* __restrict__ bmin,
                       int* __restrict__ bcnt, int* __restrict__ rlist) {
    __shared__ int lcnt[16], lbase[16], lcur[16];
    int t = threadIdx.x;
    if (t < 16) { lcnt[t] = 0; lcur[t] = 0; }
    __syncthreads();
    int row = blockIdx.x * 256 + t;
    float thr = decf(gmin[row]) + MARGIN;
    const float* bm = bmin + (size_t)row * 16;
    unsigned qual = 0;
    #pragma unroll
    for (int b = 0; b < 16; ++b)
        if (bm[b] <= thr) { qual |= (1u << b); atomicAdd(&lcnt[b], 1); }
    __syncthreads();
    if (t < 16) lbase[t] = atomicAdd(&bcnt[t], lcnt[t]);
    __syncthreads();
    #pragma unroll
    for (int b = 0; b < 16; ++b)
        if (qual & (1u << b)) {
            int p = atomicAdd(&lcur[b], 1);
            rlist[b * PADL + lbase[b] + p] = row;
        }
}

// ---------------- pass 1: emit candidates over pruned ragged tiles --------
__launch_bounds__(256, 2)
__global__ void k_pass1(const unsigned* __restrict__ zbf,
                        const uint4* __restrict__ wsw4,
                        const float* __restrict__ wwg,
                        const unsigned* __restrict__ gmin,
                        const int* __restrict__ bcnt,
                        const int* __restrict__ rlist,
                        int* __restrict__ ccnt,
                        int* __restrict__ cids) {
    const int t = threadIdx.x, wv = t >> 6, l = t & 63;
    const int q = l >> 4, n16 = l & 15;
    int bc[16];
    #pragma unroll
    for (int i = 0; i < 16; ++i) bc[i] = bcnt[i];
    int tp[17]; tp[0] = 0;
    #pragma unroll
    for (int i = 0; i < 16; ++i) tp[i + 1] = tp[i] + ((bc[i] + 63) >> 6);
    const int ntiles = tp[16];

    for (int tile = blockIdx.x * 4 + wv; tile < ntiles; tile += 2048) {
        int b = 0, tpb = 0, nb = bc[0];
        #pragma unroll
        for (int i = 1; i < 16; ++i)
            if (tp[i] <= tile) { b = i; tpb = tp[i]; nb = bc[i]; }
        const int lim = nb - (tile - tpb) * 64;
        const int* rl = rlist + b * PADL + (tile - tpb) * 64;

        union U { uint4 u; short8 s; } afr[4][8];
        #pragma unroll
        for (int s = 0; s < 4; ++s) {
            int idx = s * 16 + n16;
            int r = (idx < lim) ? rl[idx] : -1;
            int rr = r < 0 ? 0 : r;
            const char* zb = (const char*)zbf + ((size_t)rr << 9) + q * 16;
            #pragma unroll
            for (int c = 0; c < 8; ++c) afr[s][c].u = *(const uint4*)(zb + c * 64);
        }
        int rowid[16];
        float thr[16];
        #pragma unroll
        for (int i = 0; i < 16; ++i) {
            int idx = (i >> 2) * 16 + q * 4 + (i & 3);
            int r = (idx < lim) ? rl[idx] : -1;
            rowid[i] = r;
            thr[i] = -3.0e38f;
            if (r >= 0) thr[i] = decf(gmin[r]) + MARGIN;
        }

        #pragma unroll 2
        for (int g = 0; g < 16; ++g) {
            const int gg = b * 16 + g;
            const uint4* wp = wsw4 + (size_t)gg * 512 + l;
            f32x4 acc[4];
            #pragma unroll
            for (int s = 0; s < 4; ++s) acc[s] = (f32x4){0.f, 0.f, 0.f, 0.f};
            #pragma unroll
            for (int c = 0; c < 8; ++c) {
                U bf; bf.u = wp[c * 64];
                #pragma unroll
                for (int s = 0; s < 4; ++s)
                    acc[s] = __builtin_amdgcn_mfma_f32_16x16x32_bf16(afr[s][c].s, bf.s, acc[s], 0, 0, 0);
            }
            float wwv = wwg[gg * 16 + n16];
            #pragma unroll
            for (int s = 0; s < 4; ++s)
                #pragma unroll
                for (int r = 0; r < 4; ++r) {
                    float core = fmaf(-2.f, acc[s][r], wwv);
                    if (core <= thr[s*4+r]) {
                        int row = rowid[s * 4 + r];
                        int pos = atomicAdd(&ccnt[row], 1);
                        if (pos < 16) cids[row * 16 + pos] = gg * 16 + n16;
                    }
                }
        }
    }
}

// ---------------- fp32 rescore of candidates ----------------
__global__ void k_refine(const float* __restrict__ z,
                         const float* __restrict__ w,
                         const float* __restrict__ zz,
                         const float* __restrict__ wwg,
                         const int* __restrict__ ccnt,
                         const int* __restrict__ cids,
                         float* __restrict__ counts,
                         int*   __restrict__ idxi,
                         float* __restrict__ idxf) {
    int l   = threadIdx.x & 63;
    int row = blockIdx.x * 4 + (threadIdx.x >> 6);
    int n = ccnt[row]; if (n > 16) n = 16;
    float4 zv = ((const float4*)(z + (size_t)row * DIMD))[l];
    float zzv = zz[row];
    float bd = 3.0e38f; int bi = 0x7fffffff;
    for (int j = 0; j < n; ++j) {
        int k = cids[row * 16 + j];
        float4 wv = ((const float4*)(w + (size_t)k * DIMD))[l];
        float s = zv.x*wv.x + zv.y*wv.y + zv.z*wv.z + zv.w*wv.w;
        #pragma unroll
        for (int off = 32; off; off >>= 1) s += __shfl_xor(s, off);
        float d = (zzv + wwg[k]) - 2.0f * s;
        if (d < bd || (d == bd && k < bi)) { bd = d; bi = k; }
    }
    if (l == 0) {
        idxi[row] = bi;
        idxf[row] = (float)bi;
        atomicAdd(&counts[bi], 1.0f);
    }
}

// ------- merged: prefix sums (offs/cursor/choffs) + cs EMA + perplexity ---
__global__ void k_mid(const float* __restrict__ counts,
                      const float* __restrict__ ema_cs,
                      int* __restrict__ offs, int* __restrict__ cursor,
                      int* __restrict__ choffs,
                      float* __restrict__ cs_io, float* __restrict__ perp) {
    __shared__ int sc[1024];
    __shared__ float2 redf[16];
    int t = threadIdx.x;
    int c[4]; int s = 0;
    #pragma unroll
    for (int i = 0; i < 4; ++i) { c[i] = (int)counts[t * 4 + i]; s += c[i]; }
    sc[t] = s;
    __syncthreads();
    for (int d = 1; d < 1024; d <<= 1) {
        int v = (t >= d) ? sc[t - d] : 0;
        __syncthreads();
        sc[t] += v;
        __syncthreads();
    }
    int o = sc[t] - s;
    #pragma unroll
    for (int i = 0; i < 4; ++i) { offs[t*4+i] = o; cursor[t*4+i] = o; o += c[i]; }
    if (t == 1023) offs[4096] = sc[1023];
    __syncthreads();

    int ch[4]; int s2 = 0;
    #pragma unroll
    for (int i = 0; i < 4; ++i) { ch[i] = (c[i] + CHK - 1) / CHK; s2 += ch[i]; }
    sc[t] = s2;
    __syncthreads();
    for (int d = 1; d < 1024; d <<= 1) {
        int v = (t >= d) ? sc[t - d] : 0;
        __syncthreads();
        sc[t] += v;
        __syncthreads();
    }
    int o2 = sc[t] - s2;
    #pragma unroll
    for (int i = 0; i < 4; ++i) { choffs[t*4+i] = o2; o2 += ch[i]; }
    if (t == 1023) choffs[4096] = sc[1023];
    __syncthreads();

    // cluster-size EMA + perplexity (counts still live in c[])
    float csd[4]; float nl = 0.f, el = 0.f;
    #pragma unroll
    for (int i = 0; i < 4; ++i) {
        float cf = (float)c[i];
        float cd = ema_cs[t * 4 + i] * 0.99f + 0.01f * cf;
        csd[i] = cd;
        nl += cd;
        float p = cf * (1.0f / 65536.0f);
        el += p * logf(p + 1e-10f);
    }
    #pragma unroll
    for (int off = 32; off; off >>= 1) { nl += __shfl_down(nl, off); el += __shfl_down(el, off); }
    if ((t & 63) == 0) redf[t >> 6] = make_float2(nl, el);
    __syncthreads();
    if (t == 0) {
        float n = 0.f, e = 0.f;
        for (int i = 0; i < 16; ++i) { n += redf[i].x; e += redf[i].y; }
        redf[0] = make_float2(n, e);
        perp[0] = expf(-e);
    }
    __syncthreads();
    float n = redf[0].x;
    float scale = n / (n + 4096.0f * 1e-5f);
    #pragma unroll
    for (int i = 0; i < 4; ++i)
        cs_io[t * 4 + i] = (csd[i] + 1e-5f) * scale;
}

// ---------------- fill inverted row lists + zero dw region ----------------
__global__ void k_fill(const int* __restrict__ idxi, int* __restrict__ cursor,
                       int* __restrict__ rows, float* __restrict__ dw) {
    int r = blockIdx.x * 256 + threadIdx.x;
    float4* p = (float4*)(dw + (size_t)r * 16);
    float4 zf = make_float4(0.f, 0.f, 0.f, 0.f);
    p[0] = zf; p[1] = zf; p[2] = zf; p[3] = zf;
    int k = idxi[r];
    int pos = atomicAdd(&cursor[k], 1);
    rows[pos] = r;
}

// ---------------- dw[k,:] += sum of z rows in chunk (chunk-parallel) ------
__global__ void k_dw(const float* __restrict__ z, const int* __restrict__ offs,
                     const int* __restrict__ choffs, const int* __restrict__ rows,
                     float* __restrict__ dw) {
    __shared__ float4 part[4][64];
    int b = blockIdx.x;
    if (b >= choffs[KCB]) return;
    int lo = 0, hi = KCB;
    while (hi - lo > 1) { int mid = (lo + hi) >> 1; if (choffs[mid] <= b) lo = mid; else hi = mid; }
    int k  = lo;
    int ci = b - choffs[k];
    int o0 = offs[k] + ci * CHK;
    int o1 = offs[k + 1]; if (o1 > o0 + CHK) o1 = o0 + CHK;
    int l = threadIdx.x & 63, j = threadIdx.x >> 6;
    float4 a = make_float4(0.f, 0.f, 0.f, 0.f);
    for (int i = o0 + j; i < o1; i += 4) {
        int r = rows[i];
        float4 v = ((const float4*)(z + (size_t)r * DIMD))[l];
        a.x += v.x; a.y += v.y; a.z += v.z; a.w += v.w;
    }
    part[j][l] = a;
    __syncthreads();
    if (j == 0) {
        float4 bb = part[0][l], c = part[1][l], d = part[2][l], e = part[3][l];
        a = make_float4(bb.x+c.x+d.x+e.x, bb.y+c.y+d.y+e.y,
                        bb.z+c.z+d.z+e.z, bb.w+c.w+d.w+e.w);
        float* p = dw + (size_t)k * DIMD + l * 4;
        if (choffs[k + 1] - choffs[k] == 1) {
            *(float4*)p = a;
        } else {
            atomicAdd(p + 0, a.x); atomicAdd(p + 1, a.y);
            atomicAdd(p + 2, a.z); atomicAdd(p + 3, a.w);
        }
    }
}

// ---------------- new_ema_w (in-place over dw) + new_weight ----------------
__global__ void k_emaw(const float* __restrict__ ema_w,
                       const float* __restrict__ cs,
                       float* __restrict__ emaw_io,
                       float* __restrict__ wout) {
    int i = (blockIdx.x * 256 + threadIdx.x) * 4;
    int k = i >> 8;
    float4 dv = *(const float4*)(emaw_io + i);
    float4 ev = *(const float4*)(ema_w + i);
    float c = cs[k];
    float4 ne;
    ne.x = ev.x * 0.99f + 0.01f * dv.x;
    ne.y = ev.y * 0.99f + 0.01f * dv.y;
    ne.z = ev.z * 0.99f + 0.01f * dv.z;
    ne.w = ev.w * 0.99f + 0.01f * dv.w;
    *(float4*)(emaw_io + i) = ne;
    float4 nw = make_float4(ne.x / c, ne.y / c, ne.z / c, ne.w / c);
    *(float4*)(wout + i) = nw;
}

// ---------------- z_q gather + straight-through + loss partial -------------
__global__ void k_zq(const float* __restrict__ z,
                     const float* __restrict__ wnew,
                     const int* __restrict__ idxi,
                     float* __restrict__ zq,
                     float* __restrict__ sqacc) {   // 256 accumulators
    __shared__ float red[4];
    int i = (blockIdx.x * 256 + threadIdx.x) * 4;
    int n = i >> 8;
    int d = i & 255;
    int k = idxi[n];
    float4 wv = *(const float4*)(wnew + (k << 8) + d);
    float4 zv = *(const float4*)(z + i);
    float4 o;
    o.x = zv.x + (wv.x - zv.x);
    o.y = zv.y + (wv.y - zv.y);
    o.z = zv.z + (wv.z - zv.z);
    o.w = zv.w + (wv.w - zv.w);
    *(float4*)(zq + i) = o;
    float dx = wv.x - zv.x, dy = wv.y - zv.y, dz = wv.z - zv.z, dw_ = wv.w - zv.w;
    float s = dx*dx + dy*dy + dz*dz + dw_*dw_;
    #pragma unroll
    for (int off = 32; off; off >>= 1) s += __shfl_down(s, off);
    int lane = threadIdx.x & 63;
    if (lane == 0) red[threadIdx.x >> 6] = s;
    __syncthreads();
    if (threadIdx.x == 0)
        atomicAdd(&sqacc[blockIdx.x & 255], red[0] + red[1] + red[2] + red[3]);
}

__global__ void k_final(const float* __restrict__ sqacc, float* __restrict__ loss) {
    __shared__ float red[4];
    int t = threadIdx.x;
    float s = sqacc[t];
    #pragma unroll
    for (int off = 32; off; off >>= 1) s += __shfl_down(s, off);
    if ((t & 63) == 0) red[t >> 6] = s;
    __syncthreads();
    if (t == 0)
        loss[0] = 1.25f * (red[0] + red[1] + red[2] + red[3]) * (1.0f / 16777216.0f);
}

extern "C" void kernel_launch(void* const* d_in, const int* in_sizes, int n_in,
                              void* d_out, int out_size, void* d_ws, size_t ws_size,
                              hipStream_t stream) {
    const float* z      = (const float*)d_in[0];
    const float* weight = (const float*)d_in[1];
    const float* ema_w  = (const float*)d_in[2];
    const float* ema_cs = (const float*)d_in[3];
    float* out = (float*)d_out;
    float* ws  = (float*)d_ws;

    int*   bcnt = (int*)ws;              // 16 ints
    float* scal = ws + 4096;             // 256 floats
    int*   idxi = (int*)(ws + 8192);     // 65536 ints

    unsigned* zbf    = (unsigned*)(out + O_ZQ);
    uint4*    wsw4   = (uint4*)(out + O_ZQ + OFF_WSW);
    int*      ccnt   = (int*)(out + O_ZQ + OFF_CCNT);
    int*      cids   = (int*)(out + O_ZQ + OFF_CIDS);
    int*      offs   = (int*)(out + O_ZQ + OFF_OFFS);
    int*      cursor = (int*)(out + O_ZQ + OFF_CUR);
    int*      rows   = (int*)(out + O_ZQ + OFF_ROWS);
    unsigned* gmin   = (unsigned*)(out + O_ZQ + OFF_GMIN);
    int*      choffs = (int*)(out + O_ZQ + OFF_CHOF);
    float*    bmin   = out + O_ZQ + OFF_BMIN;
    int*      rlist  = (int*)(out + O_ZQ + OFF_RL);
    float*    zz     = out + O_EMAW;           // dead before k_fill zeroes dw
    float*    wwg    = out + O_EMAW + 65536;

    k_prep   <<<NPTS / 4 + KCB / 4, 256, 0, stream>>>(z, weight, zbf,
                                                      (unsigned*)wsw4, zz, wwg,
                                                      gmin, ccnt, out + O_CS,
                                                      scal, bcnt);
    k_pass0  <<<512, 256, 0, stream>>>(zbf, wsw4, wwg, gmin, bmin);
    k_bsel   <<<NPTS / 256, 256, 0, stream>>>(gmin, bmin, bcnt, rlist);
    k_pass1  <<<512, 256, 0, stream>>>(zbf, wsw4, wwg, gmin, bcnt, rlist,
                                       ccnt, cids);
    k_refine <<<NPTS / 4, 256, 0, stream>>>(z, weight, zz, wwg, ccnt, cids,
                                            out + O_CS, idxi, out + O_IDX);
    k_mid    <<<1, 1024, 0, stream>>>(out + O_CS, ema_cs, offs, cursor, choffs,
                                      out + O_CS, out + O_PERP);
    k_fill   <<<NPTS / 256, 256, 0, stream>>>(idxi, cursor, rows, out + O_EMAW);
    k_dw     <<<MAXCHUNKS, 256, 0, stream>>>(z, offs, choffs, rows, out + O_EMAW);
    k_emaw   <<<(KCB * DIMD) / 1024, 256, 0, stream>>>(ema_w, out + O_CS,
                                                       out + O_EMAW, out + O_W);
    k_zq     <<<(NPTS * DIMD) / 1024, 256, 0, stream>>>(z, out + O_W, idxi,
                                                        out + O_ZQ, scal);
    k_final  <<<1, 256, 0, stream>>>(scal, out + O_LOSS);
}